// Round 5
// baseline (107.711 us; speedup 1.0000x reference)
//
#include <hip/hip_runtime.h>
#include <hip/hip_bf16.h>

#define BATCH 4
#define NPTS 8192
#define TPB 256
#define CGROUPS 32                  // colgroups per side (256 cols each)
#define GRID (8 * CGROUPS)          // 256 blocks = 1/CU, single launch

typedef short bf16x8 __attribute__((ext_vector_type(8)));
typedef float f32x16 __attribute__((ext_vector_type(16)));

__device__ __forceinline__ unsigned short b16(float f) {   // fp32 -> bf16 RNE (HW cvt)
  __hip_bfloat16 h = __float2bfloat16(f);
  return __builtin_bit_cast(unsigned short, h);
}
__device__ __forceinline__ float b2f(unsigned short h) {
  return __uint_as_float(((unsigned)h) << 16);
}

// K=16 packed rows (R8/R10/R11-verified exact, absmax 0.0):
//  roleA(x): [(-2x)h(3), (-2x)l(3), (-2x)h(3), x2h, x2l, 1,   1,  0,0,0]
//  roleB(y): [yh(3),     yh(3),     yl(3),     1,   1, y2h, y2l, 0,0,0]
// roleA.roleB = squared distance minus (-2x)l.yl (~1e-5 << 9.3e-4 threshold).
__device__ __forceinline__ void pack_halves(uint4* lo, uint4* hi, float cx,
                                            float cy, float cz, bool roleA) {
  float n2 = cx * cx + cy * cy + cz * cz;
  float vx = roleA ? -2.f * cx : cx;
  float vy = roleA ? -2.f * cy : cy;
  float vz = roleA ? -2.f * cz : cz;
  unsigned hx = b16(vx), hy = b16(vy), hz = b16(vz);
  unsigned lx = b16(vx - b2f(hx)), ly = b16(vy - b2f(hy)), lz = b16(vz - b2f(hz));
  unsigned nh = b16(n2), nl = b16(n2 - b2f(nh));
  const unsigned ONE = 0x3F80u;
  if (roleA) {
    *lo = make_uint4(hx | (hy << 16), hz | (lx << 16), ly | (lz << 16), hx | (hy << 16));
    *hi = make_uint4(hz | (nh << 16), nl | (ONE << 16), ONE, 0u);
  } else {
    *lo = make_uint4(hx | (hy << 16), hz | (hx << 16), hy | (hz << 16), lx | (ly << 16));
    *hi = make_uint4(lz | (ONE << 16), ONE | (nh << 16), nl, 0u);
  }
}

// R16 — SINGLE LAUNCH (launch count is the dominant controllable cost:
// 3->2 launches saved ~6-7 us across R13->R15; kernel-internal changes ~1 us).
// Block = (side, colgroup of 256 cols); covers ALL 8192 rows in 8 LDS
// chunks of 1024 (R12's proven chunk schedule + register prefetch of the
// next chunk's points during the tile loop). Cols packed in-register
// (R15-proven). Each block's m0/m1 are FINAL mins -> clamp, wave-sum,
// one atomicAdd per block. out[0] is zeroed by a 4-byte hipMemcpyAsync
// DMA node before the kernel (no zeroing race, no extra kernel launch).
// LDS layout lane-ordered (R12/R15-verified): unit (p>>5)*64+(p&31),
// hi-half +32; writer & reader both lane-stride-1 => 2-way alias max.
// Row-axis min in-lane (C/D: col=lane&31, row=(reg&3)+8*(reg>>2)+4*g);
// depth-3 min3 tree (R14-verified bit-identical).
__global__ __launch_bounds__(TPB, 1) void chamfer_nn(
    const float* __restrict__ pred, const float* __restrict__ gt,
    float* __restrict__ out) {
  __shared__ __align__(16) unsigned short sB[1024 * 16];   // 32 KB row frags
  __shared__ float wsum[4];

  int blk = blockIdx.x;
  int cg   = blk & (CGROUPS - 1);      // colgroup (256 cols = 8 tiles)
  int side = blk >> 5;                 // dir*4 + b
  int dir = side >> 2, b = side & 3;

  const float* As = (dir ? gt : pred) + (size_t)b * NPTS * 3;  // cols (outputs)
  const float* Bs = (dir ? pred : gt) + (size_t)b * NPTS * 3;  // rows (min'ed)

  int t = threadIdx.x, w = t >> 6, lane = t & 63;

  // Prefetch chunk 0's four row points (latency overlaps the col pack).
  float p0x, p0y, p0z, p1x, p1y, p1z, p2x, p2y, p2z, p3x, p3y, p3z;
#define LOADPTS(c) do {                                                     \
    int base = ((c) * 1024 + t) * 3;                                        \
    p0x = Bs[base];          p0y = Bs[base + 1];      p0z = Bs[base + 2];   \
    p1x = Bs[base + 768];    p1y = Bs[base + 769];    p1z = Bs[base + 770]; \
    p2x = Bs[base + 1536];   p2y = Bs[base + 1537];   p2z = Bs[base + 1538];\
    p3x = Bs[base + 2304];   p3y = Bs[base + 2305];   p3z = Bs[base + 2306];\
  } while (0)
#define PACKROW(px, py, pz, h) do {                                         \
    int p = (h) * 256 + t;                                                  \
    uint4 lo, hi;                                                           \
    pack_halves(&lo, &hi, px, py, pz, true);                                \
    unsigned short* u0 = sB + ((p >> 5) * 64 + (p & 31)) * 8;               \
    *(uint4*)u0 = lo;                                                       \
    *(uint4*)(u0 + 32 * 8) = hi;                                            \
  } while (0)

  LOADPTS(0);

  // Col operands in-register: wave w owns col tiles cg*8 + {2w, 2w+1}.
  // Lane l packs point 32*tile+(l&31); keeps lo (l<32) or hi (l>=32).
  bf16x8 af0, af1;
  {
    uint4 lo, hi;
    int gp0 = (cg * 8 + 2 * w) * 32 + (lane & 31);
    pack_halves(&lo, &hi, As[gp0 * 3], As[gp0 * 3 + 1], As[gp0 * 3 + 2], false);
    af0 = __builtin_bit_cast(bf16x8, (lane < 32) ? lo : hi);
    int gp1 = (cg * 8 + 2 * w + 1) * 32 + (lane & 31);
    pack_halves(&lo, &hi, As[gp1 * 3], As[gp1 * 3 + 1], As[gp1 * 3 + 2], false);
    af1 = __builtin_bit_cast(bf16x8, (lane < 32) ? lo : hi);
  }

  const f32x16 Z = {0.f,0.f,0.f,0.f,0.f,0.f,0.f,0.f,0.f,0.f,0.f,0.f,0.f,0.f,0.f,0.f};
  float m0 = 3.4e38f, m1 = 3.4e38f;

  #pragma unroll 1
  for (int c = 0; c < 8; ++c) {        // 8 chunks of 1024 rows
    PACKROW(p0x, p0y, p0z, 0);
    PACKROW(p1x, p1y, p1z, 1);
    PACKROW(p2x, p2y, p2z, 2);
    PACKROW(p3x, p3y, p3z, 3);
    __syncthreads();
    if (c < 7) LOADPTS(c + 1);         // in flight across the tile loop

    #pragma unroll 4
    for (int rt = 0; rt < 32; ++rt) {
      bf16x8 bf = *(const bf16x8*)(sB + (rt * 64 + lane) * 8);
      f32x16 d0 = __builtin_amdgcn_mfma_f32_32x32x16_bf16(bf, af0, Z, 0, 0, 0);
      {
        float t0 = fminf(fminf(d0[0], d0[1]), d0[2]);
        float t1 = fminf(fminf(d0[3], d0[4]), d0[5]);
        float t2 = fminf(fminf(d0[6], d0[7]), d0[8]);
        float t3 = fminf(fminf(d0[9], d0[10]), d0[11]);
        float t4 = fminf(fminf(d0[12], d0[13]), d0[14]);
        float u0 = fminf(fminf(t0, t1), d0[15]);
        float u1 = fminf(fminf(t2, t3), t4);
        m0 = fminf(fminf(m0, u0), u1);
      }
      f32x16 d1 = __builtin_amdgcn_mfma_f32_32x32x16_bf16(bf, af1, Z, 0, 0, 0);
      {
        float t0 = fminf(fminf(d1[0], d1[1]), d1[2]);
        float t1 = fminf(fminf(d1[3], d1[4]), d1[5]);
        float t2 = fminf(fminf(d1[6], d1[7]), d1[8]);
        float t3 = fminf(fminf(d1[9], d1[10]), d1[11]);
        float t4 = fminf(fminf(d1[12], d1[13]), d1[14]);
        float u0 = fminf(fminf(t0, t1), d1[15]);
        float u1 = fminf(fminf(t2, t3), t4);
        m1 = fminf(fminf(m1, u0), u1);
      }
    }
    __syncthreads();                   // sB reads done before next pack
  }
#undef LOADPTS
#undef PACKROW

  // Final per-col mins -> block sum -> one atomicAdd per block.
  m0 = fminf(m0, __shfl_xor(m0, 32, 64));   // both halves now hold merged min
  m1 = fminf(m1, __shfl_xor(m1, 32, 64));
  float s = (lane < 32) ? (fmaxf(m0, 0.f) + fmaxf(m1, 0.f)) : 0.f;
  #pragma unroll
  for (int off = 32; off > 0; off >>= 1) s += __shfl_down(s, off, 64);
  if (lane == 0) wsum[w] = s;
  __syncthreads();
  if (t == 0) {
    float tot = (wsum[0] + wsum[1]) + (wsum[2] + wsum[3]);
    atomicAdd(out, tot * (1.f / (float)(BATCH * NPTS)));
  }
}

extern "C" void kernel_launch(void* const* d_in, const int* in_sizes, int n_in,
                              void* d_out, int out_size, void* d_ws, size_t ws_size,
                              hipStream_t stream) {
  const float* pred = (const float*)d_in[0];
  const float* gt   = (const float*)d_in[1];
  float* out        = (float*)d_out;

  static const float kZero = 0.f;      // persistent host source for DMA node
  hipMemcpyAsync(out, &kZero, sizeof(float), hipMemcpyHostToDevice, stream);
  chamfer_nn<<<dim3(GRID), dim3(TPB), 0, stream>>>(pred, gt, out);
}

// Round 6
// 79.478 us; speedup vs baseline: 1.3552x; 1.3552x over previous
//
#include <hip/hip_runtime.h>
#include <hip/hip_bf16.h>

#define BATCH 4
#define NPTS 8192
#define TPB 256
#define RSPLIT 4                    // row-split partial-min slices (no atomics)
#define CGROUPS 64                  // colgroups per side (128 cols each)
#define TOTAL (2 * BATCH * NPTS)    // 65536 output slots
#define GRID (8 * CGROUPS * RSPLIT) // 2048 blocks = 8/CU (occupancy lever)

typedef short bf16x8 __attribute__((ext_vector_type(8)));
typedef float f32x16 __attribute__((ext_vector_type(16)));

__device__ __forceinline__ unsigned short b16(float f) {   // fp32 -> bf16 RNE (HW cvt)
  __hip_bfloat16 h = __float2bfloat16(f);
  return __builtin_bit_cast(unsigned short, h);
}
__device__ __forceinline__ float b2f(unsigned short h) {
  return __uint_as_float(((unsigned)h) << 16);
}

// K=16 packed rows (R8/R10/R11-verified exact, absmax 0.0):
//  roleA(x): [(-2x)h(3), (-2x)l(3), (-2x)h(3), x2h, x2l, 1,   1,  0,0,0]
//  roleB(y): [yh(3),     yh(3),     yl(3),     1,   1, y2h, y2l, 0,0,0]
// roleA.roleB = squared distance minus (-2x)l.yl (~1e-5 << 9.3e-4 threshold).
__device__ __forceinline__ void pack_halves(uint4* lo, uint4* hi, float cx,
                                            float cy, float cz, bool roleA) {
  float n2 = cx * cx + cy * cy + cz * cz;
  float vx = roleA ? -2.f * cx : cx;
  float vy = roleA ? -2.f * cy : cy;
  float vz = roleA ? -2.f * cz : cz;
  unsigned hx = b16(vx), hy = b16(vy), hz = b16(vz);
  unsigned lx = b16(vx - b2f(hx)), ly = b16(vy - b2f(hy)), lz = b16(vz - b2f(hz));
  unsigned nh = b16(n2), nl = b16(n2 - b2f(nh));
  const unsigned ONE = 0x3F80u;
  if (roleA) {
    *lo = make_uint4(hx | (hy << 16), hz | (lx << 16), ly | (lz << 16), hx | (hy << 16));
    *hi = make_uint4(hz | (nh << 16), nl | (ONE << 16), ONE, 0u);
  } else {
    *lo = make_uint4(hx | (hy << 16), hz | (hx << 16), hy | (hz << 16), lx | (ly << 16));
    *hi = make_uint4(lz | (ONE << 16), ONE | (nh << 16), nl, 0u);
  }
}

// R17 — OCCUPANCY: R16's counters showed nn is latency-bound (Occupancy 10%,
// MfmaUtil 10, VALUBusy 35, no conflicts, no HBM). At 4 waves/SIMD (R15) nn
// was ~27 us vs ~10 us issue floor; target 8 waves/SIMD (100%):
//  * 1 col-tile per wave (one f32x16 d live, not two) -> reg budget <= 64
//    (enforced by __launch_bounds__(256,8); waves/EU halves at 64/128/256).
//  * 16 KB LDS chunks (512 rows) -> 8 blocks/CU = 128 KB/CU <= 160.
//  * grid 2048 = 8 sides x 64 cgroups(128 cols) x RSPLIT 4 (2048 rows).
// Everything else is the R12/R15-verified machinery: lane-ordered LDS units
// ((p>>5)*64+(p&31), hi +32; writer/reader lane-stride-1, 2-way alias max),
// in-register col pack (lane<32 keeps lo half, else hi), in-lane row-min
// (C/D: col=lane&31, row=(reg&3)+8*(reg>>2)+4*(lane>>5)), depth-3 min3 tree,
// shfl_xor(32) half-merge, coalesced partial stores, reduce kernel sums.
__global__ __launch_bounds__(TPB, 8) void chamfer_nn(
    const float* __restrict__ pred, const float* __restrict__ gt,
    float* __restrict__ partial, float* __restrict__ out) {
  __shared__ __align__(16) unsigned short sB[512 * 16];    // 16 KB row frags

  int blk = blockIdx.x;
  int rq   = blk & (RSPLIT - 1);         // row slice (2048 rows)
  int cg   = (blk >> 2) & (CGROUPS - 1); // colgroup (128 cols = 4 tiles)
  int side = blk >> 8;                   // dir*4 + b
  int dir = side >> 2, b = side & 3;

  const float* As = (dir ? gt : pred) + (size_t)b * NPTS * 3;  // cols (outputs)
  const float* Bs = (dir ? pred : gt) + (size_t)b * NPTS * 3;  // rows (min'ed)

  int t = threadIdx.x, w = t >> 6, lane = t & 63;
  if (blk == 0 && t == 0) out[0] = 0.f;   // zero accumulator for reduce pass

  int rowbase = rq * 2048;

  // Prefetch chunk 0's two row points (latency overlaps the col pack).
  float p0x, p0y, p0z, p1x, p1y, p1z;
#define LOADPTS(c) do {                                                     \
    int base = (rowbase + (c) * 512 + t) * 3;                               \
    p0x = Bs[base];        p0y = Bs[base + 1];    p0z = Bs[base + 2];       \
    p1x = Bs[base + 768];  p1y = Bs[base + 769];  p1z = Bs[base + 770];     \
  } while (0)
#define PACKROW(px, py, pz, h) do {                                         \
    int p = (h) * 256 + t;                                                  \
    uint4 lo, hi;                                                           \
    pack_halves(&lo, &hi, px, py, pz, true);                                \
    unsigned short* u0 = sB + ((p >> 5) * 64 + (p & 31)) * 8;               \
    *(uint4*)u0 = lo;                                                       \
    *(uint4*)(u0 + 32 * 8) = hi;                                            \
  } while (0)

  LOADPTS(0);

  // Col operand in-register: wave w owns col tile cg*4 + w.
  // Lane l packs point 32*tile+(l&31); keeps lo (l<32) or hi (l>=32).
  bf16x8 af;
  {
    uint4 lo, hi;
    int gp = (cg * 4 + w) * 32 + (lane & 31);
    pack_halves(&lo, &hi, As[gp * 3], As[gp * 3 + 1], As[gp * 3 + 2], false);
    af = __builtin_bit_cast(bf16x8, (lane < 32) ? lo : hi);
  }

  const f32x16 Z = {0.f,0.f,0.f,0.f,0.f,0.f,0.f,0.f,0.f,0.f,0.f,0.f,0.f,0.f,0.f,0.f};
  float m = 3.4e38f;

  #pragma unroll 1
  for (int c = 0; c < 4; ++c) {        // 4 chunks of 512 rows
    PACKROW(p0x, p0y, p0z, 0);
    PACKROW(p1x, p1y, p1z, 1);
    __syncthreads();
    if (c < 3) LOADPTS(c + 1);         // in flight across the tile loop

    #pragma unroll 2
    for (int rt = 0; rt < 16; ++rt) {
      bf16x8 bf = *(const bf16x8*)(sB + (rt * 64 + lane) * 8);
      f32x16 d = __builtin_amdgcn_mfma_f32_32x32x16_bf16(bf, af, Z, 0, 0, 0);
      float t0 = fminf(fminf(d[0], d[1]), d[2]);
      float t1 = fminf(fminf(d[3], d[4]), d[5]);
      float t2 = fminf(fminf(d[6], d[7]), d[8]);
      float t3 = fminf(fminf(d[9], d[10]), d[11]);
      float t4 = fminf(fminf(d[12], d[13]), d[14]);
      float u0 = fminf(fminf(t0, t1), d[15]);
      float u1 = fminf(fminf(t2, t3), t4);
      m = fminf(fminf(m, u0), u1);
    }
    __syncthreads();                   // sB reads done before next pack
  }
#undef LOADPTS
#undef PACKROW

  m = fminf(m, __shfl_xor(m, 32, 64));      // merge complementary row halves
  if (lane < 32) {
    partial[(size_t)rq * TOTAL + (size_t)side * NPTS + cg * 128 + w * 32 + lane]
        = fmaxf(m, 0.f);
  }
}

// Reduce: min over RSPLIT partials per slot, block-sum, one atomicAdd/block.
// out[0] was zeroed by chamfer_nn (stream-ordered before this kernel).
__global__ __launch_bounds__(TPB) void chamfer_reduce(
    const float* __restrict__ partial, float* __restrict__ out) {
  int t = threadIdx.x;
  int s = blockIdx.x * TPB + t;       // slot 0..65535
  float v = partial[s];
  #pragma unroll
  for (int r = 1; r < RSPLIT; ++r)
    v = fminf(v, partial[(size_t)r * TOTAL + s]);
  #pragma unroll
  for (int off = 32; off > 0; off >>= 1) v += __shfl_down(v, off, 64);
  __shared__ float wsum[4];
  int wave = t >> 6, lane = t & 63;
  if (lane == 0) wsum[wave] = v;
  __syncthreads();
  if (t == 0) {
    float tot = (wsum[0] + wsum[1]) + (wsum[2] + wsum[3]);
    atomicAdd(out, tot * (1.f / (float)(BATCH * NPTS)));
  }
}

extern "C" void kernel_launch(void* const* d_in, const int* in_sizes, int n_in,
                              void* d_out, int out_size, void* d_ws, size_t ws_size,
                              hipStream_t stream) {
  const float* pred = (const float*)d_in[0];
  const float* gt   = (const float*)d_in[1];
  float* out        = (float*)d_out;
  float* partial    = (float*)d_ws;   // RSPLIT x 65536 floats = 1 MB

  chamfer_nn<<<dim3(GRID), dim3(TPB), 0, stream>>>(pred, gt, partial, out);
  chamfer_reduce<<<dim3(TOTAL / TPB), dim3(TPB), 0, stream>>>(partial, out);
}

// Round 7
// 78.446 us; speedup vs baseline: 1.3731x; 1.0132x over previous
//
#include <hip/hip_runtime.h>
#include <hip/hip_bf16.h>

#define BATCH 4
#define NPTS 8192
#define TPB 1024                    // 16 waves/block
#define RSPLIT 8                    // row-split partial-min slices (no atomics)
#define CGROUPS 8                   // colgroups per side (1024 cols each)
#define TOTAL (2 * BATCH * NPTS)    // 65536 output slots
#define GRID (8 * CGROUPS * RSPLIT) // 512 blocks = 2/CU -> 32 waves/CU (100%)

typedef short bf16x8 __attribute__((ext_vector_type(8)));
typedef float f32x16 __attribute__((ext_vector_type(16)));

__device__ __forceinline__ unsigned short b16(float f) {   // fp32 -> bf16 RNE (HW cvt)
  __hip_bfloat16 h = __float2bfloat16(f);
  return __builtin_bit_cast(unsigned short, h);
}
__device__ __forceinline__ float b2f(unsigned short h) {
  return __uint_as_float(((unsigned)h) << 16);
}

// K=16 packed rows (R8/R10/R11-verified exact, absmax 0.0):
//  roleA(x): [(-2x)h(3), (-2x)l(3), (-2x)h(3), x2h, x2l, 1,   1,  0,0,0]
//  roleB(y): [yh(3),     yh(3),     yl(3),     1,   1, y2h, y2l, 0,0,0]
// roleA.roleB = squared distance minus (-2x)l.yl (~1e-5 << 9.3e-4 threshold).
__device__ __forceinline__ void pack_halves(uint4* lo, uint4* hi, float cx,
                                            float cy, float cz, bool roleA) {
  float n2 = cx * cx + cy * cy + cz * cz;
  float vx = roleA ? -2.f * cx : cx;
  float vy = roleA ? -2.f * cy : cy;
  float vz = roleA ? -2.f * cz : cz;
  unsigned hx = b16(vx), hy = b16(vy), hz = b16(vz);
  unsigned lx = b16(vx - b2f(hx)), ly = b16(vy - b2f(hy)), lz = b16(vz - b2f(hz));
  unsigned nh = b16(n2), nl = b16(n2 - b2f(nh));
  const unsigned ONE = 0x3F80u;
  if (roleA) {
    *lo = make_uint4(hx | (hy << 16), hz | (lx << 16), ly | (lz << 16), hx | (hy << 16));
    *hi = make_uint4(hz | (nh << 16), nl | (ONE << 16), ONE, 0u);
  } else {
    *lo = make_uint4(hx | (hy << 16), hz | (hx << 16), hy | (hz << 16), lx | (ly << 16));
    *hi = make_uint4(lz | (ONE << 16), ONE | (nh << 16), nl, 0u);
  }
}

// R18 — R15's proven single-barrier structure at 100% occupancy.
// Post-mortem R17: occupancy gain was eaten by 4x pack redundancy + 8
// barriers/block. Here: TPB=1024 (16 waves), block = 1024 cols x 1024 rows,
// ONE barrier, row packs amortized over 16 waves (0.52M total packs,
// half of R15, 1/8 of R17). 2 blocks/CU x 16 waves = 32 waves/CU = 8/SIMD
// (enforced by __launch_bounds__(1024,8) -> VGPR <= 64; R16 measured this
// exact inner loop at 52 VGPR). Inner loop = R16's verified af0/af1 +
// sequential d0/d1 + depth-3 min3 trees. LDS lane-ordered units
// ((p>>5)*64+(p&31), hi +32; writer/reader lane-stride-1, 0 conflicts
// measured R12-R16). In-lane row-min (C/D: col=lane&31,
// row=(reg&3)+8*(reg>>2)+4*(lane>>5)); shfl_xor(32) merge; coalesced
// 128B partial stores; separate reduce kernel (2-launch, R15-proven).
__global__ __launch_bounds__(TPB, 8) void chamfer_nn(
    const float* __restrict__ pred, const float* __restrict__ gt,
    float* __restrict__ partial, float* __restrict__ out) {
  __shared__ __align__(16) unsigned short sB[1024 * 16];   // 32 KB row frags

  int blk = blockIdx.x;
  int rq   = blk & (RSPLIT - 1);         // row slice (1024 rows = 32 tiles)
  int cg   = (blk >> 3) & (CGROUPS - 1); // colgroup (1024 cols = 32 tiles)
  int side = blk >> 6;                   // dir*4 + b
  int dir = side >> 2, b = side & 3;

  const float* As = (dir ? gt : pred) + (size_t)b * NPTS * 3;  // cols (outputs)
  const float* Bs = (dir ? pred : gt) + (size_t)b * NPTS * 3;  // rows (min'ed)

  int t = threadIdx.x, w = t >> 6, lane = t & 63;
  if (blk == 0 && t == 0) out[0] = 0.f;   // zero accumulator for reduce pass

  // ---- Stage rows: 1 point/thread into lane-ordered LDS units. ----
  {
    int gp = rq * 1024 + t;
    uint4 lo, hi;
    pack_halves(&lo, &hi, Bs[gp * 3], Bs[gp * 3 + 1], Bs[gp * 3 + 2], true);
    unsigned short* u0 = sB + ((t >> 5) * 64 + (t & 31)) * 8;
    *(uint4*)u0 = lo;
    *(uint4*)(u0 + 32 * 8) = hi;
  }

  // ---- Col operands in-register: wave w owns col tiles 2w, 2w+1.
  // Lane l packs point 32*tile+(l&31); keeps lo (l<32) or hi (l>=32).
  bf16x8 af0, af1;
  {
    uint4 lo, hi;
    int gp0 = cg * 1024 + (2 * w) * 32 + (lane & 31);
    pack_halves(&lo, &hi, As[gp0 * 3], As[gp0 * 3 + 1], As[gp0 * 3 + 2], false);
    af0 = __builtin_bit_cast(bf16x8, (lane < 32) ? lo : hi);
    int gp1 = gp0 + 32;
    pack_halves(&lo, &hi, As[gp1 * 3], As[gp1 * 3 + 1], As[gp1 * 3 + 2], false);
    af1 = __builtin_bit_cast(bf16x8, (lane < 32) ? lo : hi);
  }

  __syncthreads();   // single barrier: rows staged

  const f32x16 Z = {0.f,0.f,0.f,0.f,0.f,0.f,0.f,0.f,0.f,0.f,0.f,0.f,0.f,0.f,0.f,0.f};
  float m0 = 3.4e38f, m1 = 3.4e38f;

  #pragma unroll 2
  for (int rt = 0; rt < 32; ++rt) {
    bf16x8 bf = *(const bf16x8*)(sB + (rt * 64 + lane) * 8);
    f32x16 d0 = __builtin_amdgcn_mfma_f32_32x32x16_bf16(bf, af0, Z, 0, 0, 0);
    {
      float t0 = fminf(fminf(d0[0], d0[1]), d0[2]);
      float t1 = fminf(fminf(d0[3], d0[4]), d0[5]);
      float t2 = fminf(fminf(d0[6], d0[7]), d0[8]);
      float t3 = fminf(fminf(d0[9], d0[10]), d0[11]);
      float t4 = fminf(fminf(d0[12], d0[13]), d0[14]);
      float u0 = fminf(fminf(t0, t1), d0[15]);
      float u1 = fminf(fminf(t2, t3), t4);
      m0 = fminf(fminf(m0, u0), u1);
    }
    f32x16 d1 = __builtin_amdgcn_mfma_f32_32x32x16_bf16(bf, af1, Z, 0, 0, 0);
    {
      float t0 = fminf(fminf(d1[0], d1[1]), d1[2]);
      float t1 = fminf(fminf(d1[3], d1[4]), d1[5]);
      float t2 = fminf(fminf(d1[6], d1[7]), d1[8]);
      float t3 = fminf(fminf(d1[9], d1[10]), d1[11]);
      float t4 = fminf(fminf(d1[12], d1[13]), d1[14]);
      float u0 = fminf(fminf(t0, t1), d1[15]);
      float u1 = fminf(fminf(t2, t3), t4);
      m1 = fminf(fminf(m1, u0), u1);
    }
  }

  m0 = fminf(m0, __shfl_xor(m0, 32, 64));   // merge complementary row halves
  m1 = fminf(m1, __shfl_xor(m1, 32, 64));
  if (lane < 32) {
    float* dst = partial + (size_t)rq * TOTAL + (size_t)side * NPTS + cg * 1024;
    dst[(2 * w) * 32 + lane]     = fmaxf(m0, 0.f);
    dst[(2 * w + 1) * 32 + lane] = fmaxf(m1, 0.f);
  }
}

// Reduce: min over RSPLIT partials per slot, block-sum, one atomicAdd/block.
// out[0] was zeroed by chamfer_nn (stream-ordered before this kernel).
__global__ __launch_bounds__(256) void chamfer_reduce(
    const float* __restrict__ partial, float* __restrict__ out) {
  int t = threadIdx.x;
  int s = blockIdx.x * 256 + t;       // slot 0..65535
  float v = partial[s];
  #pragma unroll
  for (int r = 1; r < RSPLIT; ++r)
    v = fminf(v, partial[(size_t)r * TOTAL + s]);
  #pragma unroll
  for (int off = 32; off > 0; off >>= 1) v += __shfl_down(v, off, 64);
  __shared__ float wsum[4];
  int wave = t >> 6, lane = t & 63;
  if (lane == 0) wsum[wave] = v;
  __syncthreads();
  if (t == 0) {
    float tot = (wsum[0] + wsum[1]) + (wsum[2] + wsum[3]);
    atomicAdd(out, tot * (1.f / (float)(BATCH * NPTS)));
  }
}

extern "C" void kernel_launch(void* const* d_in, const int* in_sizes, int n_in,
                              void* d_out, int out_size, void* d_ws, size_t ws_size,
                              hipStream_t stream) {
  const float* pred = (const float*)d_in[0];
  const float* gt   = (const float*)d_in[1];
  float* out        = (float*)d_out;
  float* partial    = (float*)d_ws;   // RSPLIT x 65536 floats = 2 MB

  chamfer_nn<<<dim3(GRID), dim3(TPB), 0, stream>>>(pred, gt, partial, out);
  chamfer_reduce<<<dim3(TOTAL / 256), dim3(256), 0, stream>>>(partial, out);
}